// Round 12
// baseline (128.216 us; speedup 1.0000x reference)
//
#include <hip/hip_runtime.h>
#include <math.h>

#define B_ 16
#define L_ 256
#define D_ 64

#define CHUNK 16
#define WARM  6                     // conservative (R10-proven); level-5 row exact at tw+5
#define NCH   (L_ / CHUNK)

#define PITCH 64                    // 16 quads/slot; phys quad = dq ^ v; edge floats via
                                    // scalar LDS reads (no pads, no DPP)
#define NSLOT 127                   // slot 0 = zeros (concat row -1); 1..64 = x rows 0..63;
                                    // 65..126 = h(t-1) rows 0..61
#define FBUF  (NSLOT * PITCH)       // 8128 floats
#define LDSZ  (2 * FBUF)            // 16256 floats = 63.5 KB

// fast tanh via v_exp_f32: overflow/NaN-safe, ~1e-7 rel error (thr 1e-2)
__device__ __forceinline__ float ftanh(float x) {
    float ax = fabsf(x);
    float e  = __builtin_amdgcn_exp2f(-2.8853900818f * ax);   // e^{-2ax}
    float r  = (1.0f - e) * __builtin_amdgcn_rcpf(1.0f + e);
    return copysignf(r, x);
}

// DPP wave shifts with zero boundary fill (bound_ctrl=1) — used ONLY in scan63
// (single fully-active wave; validated there since R3).
__device__ __forceinline__ float dpp_shr1(float x) {
    int r = __builtin_amdgcn_update_dpp(0, __float_as_int(x), 0x138, 0xF, 0xF, true);
    return __int_as_float(r);
}
__device__ __forceinline__ float dpp_shl1(float x) {
    int r = __builtin_amdgcn_update_dpp(0, __float_as_int(x), 0x130, 0xF, 0xF, true);
    return __int_as_float(r);
}

// ---------------------------------------------------------------------------
// fused_layer: rows 0..62 for a (b, t-chunk), serial over t. Full x(t) frame +
// h(t-1) rows 0..61 in one double-buffered XOR-swizzled LDS frame. Per tap
// slot a lane reads its own 2 quads (cols c0..c0+7) as 2x ds_read_b128, plus
// the 2 edge floats (cols c0-1, c0+8) as scalar LDS reads at clamped offsets
// (masked to 0 at l8==0/7 where the column zero-pad applies anyway).
// Slot s holds concat row s-1; data quad dq of slot s at phys quad dq^((s>>1)&7).
// WARM=6 warm-up steps make chunk starts exact (level-k rows exact at tw+k,
// k<=5; +1 margin). Row 63 (truly recurrent) is finished by scan63.
__global__ __launch_bounds__(512, 1) void fused_layer(
        const float* __restrict__ X, float* __restrict__ H,
        const float* __restrict__ Wl, const float* __restrict__ bl) {
    __shared__ float lds[LDSZ];

    const int tid    = threadIdx.x;
    const int b      = blockIdx.x >> 4;
    const int ch     = blockIdx.x & (NCH - 1);
    const int T0     = ch * CHUNK;
    const int tw     = (T0 >= WARM) ? (T0 - WARM) : 0;
    const int tend   = T0 + CHUNK;
    const int btbase = b * L_;

    const int r   = tid >> 3;                          // row 0..63
    const int l8  = tid & 7;
    const int q0  = l8 << 1;                           // own data quads q0, q0+1
    // x-staging offsets (all 512 threads)
    const int sx  = r + 1;
    const int vx  = (sx >> 1) & 7;
    const int xw0 = sx * PITCH + ((q0 ^ vx) << 2);
    const int xw1 = sx * PITCH + (((q0 + 1) ^ vx) << 2);
    // compute mapping: threads 0..503 -> output rows 0..62
    const bool comp = tid < 504;
    const int  i    = r;
    const int  c0   = l8 << 3;
    const int  sh   = 65 + i;                          // h-store slot (i<=61)
    const int  vh   = (sh >> 1) & 7;
    const int  hw0  = sh * PITCH + ((q0 ^ vh) << 2);
    const int  hw1  = sh * PITCH + (((q0 + 1) ^ vh) << 2);
    const bool le0  = (l8 == 0);
    const bool le7  = (l8 == 7);
    const int  qm   = le0 ? q0 : (q0 - 1);             // clamped; value masked
    const int  qp   = le7 ? q0 : (q0 + 2);

    // per-ki read offsets (slots 2i..2i+2), precomputed once
    int ro0[3], ro1[3], rle[3], rre[3];
#pragma unroll
    for (int ki = 0; ki < 3; ++ki) {
        const int s = 2 * i + ki;
        const int v = (s >> 1) & 7;
        const int sb = s * PITCH;
        ro0[ki] = sb + ((q0 ^ v) << 2);
        ro1[ki] = sb + (((q0 + 1) ^ v) << 2);
        rle[ki] = sb + ((qm ^ v) << 2) + 3;            // data col c0-1 (pos 3 of quad q0-1)
        rre[ki] = sb + ((qp ^ v) << 2);                // data col c0+8 (pos 0 of quad q0+2)
    }

    float w[9];
#pragma unroll
    for (int k = 0; k < 9; ++k) w[k] = Wl[k];
    const float bias = bl[0];
    const float4 z4 = make_float4(0.f, 0.f, 0.f, 0.f);

    // zero both frames (slot 0 + h(-1)=0; warm-up fixes the rest)
    for (int k = tid; k < LDSZ / 4; k += 512)
        reinterpret_cast<float4*>(lds)[k] = z4;
    __syncthreads();

    float* cur = lds;
    float* nxt = lds + FBUF;

    // stage x(tw) into cur ((r<<6)+(l8<<3) == tid<<3)
    {
        const float* xg = X + (((size_t)(btbase + tw)) << 12) + (tid << 3);
        *reinterpret_cast<float4*>(cur + xw0) = reinterpret_cast<const float4*>(xg)[0];
        *reinterpret_cast<float4*>(cur + xw1) = reinterpret_cast<const float4*>(xg)[1];
    }
    // register prefetch x(tw+1)
    float4 pa, pb;
    {
        const int t1 = (tw + 1 < L_) ? tw + 1 : L_ - 1;
        const float* xg = X + (((size_t)(btbase + t1)) << 12) + (tid << 3);
        pa = reinterpret_cast<const float4*>(xg)[0];
        pb = reinterpret_cast<const float4*>(xg)[1];
    }
    __syncthreads();

    for (int t = tw; t < tend; ++t) {
        // issue x(t+2) loads — 2 steps deep, off the serial chain
        const int t2 = (t + 2 < L_) ? t + 2 : L_ - 1;
        const float* xg = X + (((size_t)(btbase + t2)) << 12) + (tid << 3);
        const float4 na = reinterpret_cast<const float4*>(xg)[0];
        const float4 nb = reinterpret_cast<const float4*>(xg)[1];

        if (comp) {
            float acc[8];
#pragma unroll
            for (int k = 0; k < 8; ++k) acc[k] = bias;
#pragma unroll
            for (int ki = 0; ki < 3; ++ki) {
                const float4 o0 = *reinterpret_cast<const float4*>(cur + ro0[ki]);
                const float4 o1 = *reinterpret_cast<const float4*>(cur + ro1[ki]);
                const float eLv = cur[rle[ki]];
                const float eRv = cur[rre[ki]];
                // e[0..9] = cols c0-1 .. c0+8 of concat row 2i-1+ki
                float e[10];
                e[0] = le0 ? 0.f : eLv;
                e[1] = o0.x; e[2] = o0.y; e[3] = o0.z; e[4] = o0.w;
                e[5] = o1.x; e[6] = o1.y; e[7] = o1.z; e[8] = o1.w;
                e[9] = le7 ? 0.f : eRv;
                const float wa = w[ki*3], wb = w[ki*3+1], wc = w[ki*3+2];
#pragma unroll
                for (int k = 0; k < 8; ++k)
                    acc[k] = fmaf(wa, e[k], fmaf(wb, e[k+1], fmaf(wc, e[k+2], acc[k])));
            }
            float o[8];
#pragma unroll
            for (int k = 0; k < 8; ++k) o[k] = ftanh(acc[k]);

            if (t >= T0) {                             // skip warm-up writes
                float* gd = H + (((size_t)(btbase + t)) << 12) + (i << 6) + c0;
                *reinterpret_cast<float4*>(gd)     = make_float4(o[0],o[1],o[2],o[3]);
                *reinterpret_cast<float4*>(gd + 4) = make_float4(o[4],o[5],o[6],o[7]);
            }
            if (i <= 61) {                             // h row for next step
                *reinterpret_cast<float4*>(nxt + hw0) = make_float4(o[0],o[1],o[2],o[3]);
                *reinterpret_cast<float4*>(nxt + hw1) = make_float4(o[4],o[5],o[6],o[7]);
            }
        }
        {   // commit x(t+1) into nxt
            *reinterpret_cast<float4*>(nxt + xw0) = pa;
            *reinterpret_cast<float4*>(nxt + xw1) = pb;
        }
        __syncthreads();
        pa = na; pb = nb;
        float* tmp = cur; cur = nxt; nxt = tmp;
    }
}

// ---------------------------------------------------------------------------
// Sequential scan for row 63 (reads rows 61/62 from global, written above).
#define SDEPTH 16
__global__ void scan63(float* __restrict__ dst,
                       const float* __restrict__ src,
                       const float* __restrict__ Wl,
                       const float* __restrict__ bl) {
    const int b = blockIdx.x;
    const int j = threadIdx.x;                         // 0..63, one wave
    float w[9];
#pragma unroll
    for (int k = 0; k < 9; ++k) w[k] = Wl[k];
    const float bias = bl[0];

    const size_t ST = (size_t)D_ * D_;
    const float* s61 = src + (size_t)b * L_ * ST + 61 * 64 + j;
    const float* s62 = src + (size_t)b * L_ * ST + 62 * 64 + j;
    float*       d63 = dst + (size_t)b * L_ * ST + 63 * 64 + j;

    float s = ftanh(bias);                             // t=0: h_{-1}=0
    d63[0] = s;

    float p61[SDEPTH], p62[SDEPTH];
#pragma unroll
    for (int u = 0; u < SDEPTH; ++u) {
        p61[u] = s61[(size_t)u * ST];
        p62[u] = s62[(size_t)u * ST];
    }

    for (int t0 = 1; t0 < 256; t0 += SDEPTH) {
#pragma unroll
        for (int u = 0; u < SDEPTH; ++u) {
            const int t = t0 + u;
            if (t > 255) break;
            const float r61 = p61[u], r62 = p62[u];
            int tp = t + SDEPTH - 1;
            if (tp > 255) tp = 255;
            p61[u] = s61[(size_t)tp * ST];
            p62[u] = s62[(size_t)tp * ST];
            float l1 = dpp_shr1(r61), q1 = dpp_shl1(r61);
            float l2 = dpp_shr1(r62), q2 = dpp_shl1(r62);
            float p = bias;
            p = fmaf(w[0], l1, p); p = fmaf(w[1], r61, p); p = fmaf(w[2], q1, p);
            p = fmaf(w[3], l2, p); p = fmaf(w[4], r62, p); p = fmaf(w[5], q2, p);
            float ls = dpp_shr1(s), rs = dpp_shl1(s);
            float z = fmaf(w[6], ls, fmaf(w[7], s, fmaf(w[8], rs, p)));
            s = ftanh(z);
            d63[(size_t)t * ST] = s;
        }
    }
}

extern "C" void kernel_launch(void* const* d_in, const int* in_sizes, int n_in,
                              void* d_out, int out_size, void* d_ws, size_t ws_size,
                              hipStream_t stream) {
    const float* x    = (const float*)d_in[0];   // (B,L,D,D)
    const float* W    = (const float*)d_in[1];   // (2,1,1,3,3)
    const float* bias = (const float*)d_in[2];   // (2,)
    float* out = (float*)d_out;
    float* h1  = (float*)d_ws;

    for (int l = 0; l < 2; ++l) {
        const float* X  = (l == 0) ? x  : h1;
        float*       H  = (l == 0) ? h1 : out;
        fused_layer<<<B_ * NCH, 512, 0, stream>>>(X, H, W + l * 9, bias + l);
        scan63<<<B_, 64, 0, stream>>>(H, H, W + l * 9, bias + l);
    }
}